// Round 2
// baseline (223.919 us; speedup 1.0000x reference)
//
#include <hip/hip_runtime.h>
#include <stdint.h>

// WaveletLayer fused kernel (fp32 I/O): db2 DWT (symmetric ext) ->
// scale cD by weight[0] -> db2 IDWT -> leaky_relu(0.01).
// One 256-thread block handles ROWS=2 rows of N=512; 16 B/lane load+store.
//
// Index algebra (verified vs the JAX reference):
//   ext[j] = x[m], m = j-2 reflected (m<0 -> -m-1; m>=n -> 2n-1-m)
//   cA[i]  = DL3*ext[2i] + DL2*ext[2i+1] + DL1*ext[2i+2] + DL0*ext[2i+3]
//   interior i in [1,255]: taps = x[2i-2 .. 2i+1]
//   i=0   : taps = x1,x0,x0,x1      i=256 : taps = x510,x511,x511,x510
//   idwt, i = j>>1:
//   even j: z = RL2*A[i] + RL0*A[i+1] + RH2*D[i] + RH0*D[i+1]
//   odd  j: z = RL3*A[i] + RL1*A[i+1] + RH3*D[i] + RH1*D[i+1]
//   with D = weight[0] * cD.

#define N     512
#define NC    257          // N/2 + 1 coefficients per band
#define ROWS  2
#define CPAD  260          // padded LDS stride for coeff arrays

__global__ __launch_bounds__(256) void wavelet_kernel(
    const float* __restrict__ x,
    const float* __restrict__ w,
    float* __restrict__ out)
{
    // db2 filter bank (pywt), fp32
    constexpr float DL0 = -0.12940952255092145f, DL1 = 0.22414386804185735f,
                    DL2 =  0.836516303737469f,   DL3 = 0.48296291314469025f;
    constexpr float DH0 = -0.48296291314469025f, DH1 = 0.836516303737469f,
                    DH2 = -0.22414386804185735f, DH3 = -0.12940952255092145f;
    constexpr float RL0 =  0.48296291314469025f, RL1 = 0.836516303737469f,
                    RL2 =  0.22414386804185735f, RL3 = -0.12940952255092145f;
    constexpr float RH0 = -0.12940952255092145f, RH1 = -0.22414386804185735f,
                    RH2 =  0.836516303737469f,   RH3 = -0.48296291314469025f;

    __shared__ float xs[ROWS][N];
    __shared__ float sA[ROWS][CPAD];
    __shared__ float sD[ROWS][CPAD];
    __shared__ float wf[NC];

    const int tid = threadIdx.x;
    const size_t base = (size_t)blockIdx.x * (ROWS * N);

    // ---- stage weight row 0 (first NC floats of the (2,257) weight) ----
    wf[tid] = w[tid];                  // 0..255
    if (tid == 0) wf[256] = w[256];

    // ---- global -> LDS: one float4 (16 B) per thread, coalesced ----
    {
        float4 v = ((const float4*)(x + base))[tid];
        int e = tid << 2;              // flat element index within block tile
        int r = e >> 9;
        int c = e & (N - 1);
        *(float4*)&xs[r][c] = v;
    }
    __syncthreads();

    // ---- DWT: cA[i], cD[i]*w0[i] for i in [0,256] per row ----
    #pragma unroll
    for (int r = 0; r < ROWS; ++r) {
        {
            int i = tid;
            float v0, v1, v2, v3;
            if (i == 0) {
                v0 = xs[r][1]; v1 = xs[r][0]; v2 = xs[r][0]; v3 = xs[r][1];
            } else {
                int b = 2 * i - 2;
                v0 = xs[r][b]; v1 = xs[r][b + 1]; v2 = xs[r][b + 2]; v3 = xs[r][b + 3];
            }
            float a = DL3 * v0 + DL2 * v1 + DL1 * v2 + DL0 * v3;
            float d = DH3 * v0 + DH2 * v1 + DH1 * v2 + DH0 * v3;
            sA[r][i] = a;
            sD[r][i] = d * wf[i];
        }
        if (tid == 0) {  // i = 256
            float v0 = xs[r][510], v1 = xs[r][511], v2 = xs[r][511], v3 = xs[r][510];
            float a = DL3 * v0 + DL2 * v1 + DL1 * v2 + DL0 * v3;
            float d = DH3 * v0 + DH2 * v1 + DH1 * v2 + DH0 * v3;
            sA[r][256] = a;
            sD[r][256] = d * wf[256];
        }
    }
    __syncthreads();

    // ---- IDWT + leaky_relu: 4 consecutive outputs per thread, 16 B store ----
    {
        int e  = tid << 2;
        int r  = e >> 9;
        int c  = e & (N - 1);
        int ib = c >> 1;               // need A/D[ib .. ib+2]
        float A0 = sA[r][ib],     D0 = sD[r][ib];
        float A1 = sA[r][ib + 1], D1 = sD[r][ib + 1];
        float A2 = sA[r][ib + 2], D2 = sD[r][ib + 2];

        float z0 = RL2 * A0 + RL0 * A1 + RH2 * D0 + RH0 * D1;
        float z1 = RL3 * A0 + RL1 * A1 + RH3 * D0 + RH1 * D1;
        float z2 = RL2 * A1 + RL0 * A2 + RH2 * D1 + RH0 * D2;
        float z3 = RL3 * A1 + RL1 * A2 + RH3 * D1 + RH1 * D2;

        float4 o;
        o.x = z0 >= 0.f ? z0 : 0.01f * z0;
        o.y = z1 >= 0.f ? z1 : 0.01f * z1;
        o.z = z2 >= 0.f ? z2 : 0.01f * z2;
        o.w = z3 >= 0.f ? z3 : 0.01f * z3;
        ((float4*)(out + base))[tid] = o;
    }
}

extern "C" void kernel_launch(void* const* d_in, const int* in_sizes, int n_in,
                              void* d_out, int out_size, void* d_ws, size_t ws_size,
                              hipStream_t stream) {
    const float* x = (const float*)d_in[0];
    const float* w = (const float*)d_in[1];
    float* out = (float*)d_out;

    int rows   = in_sizes[0] / N;      // 65536
    int blocks = rows / ROWS;          // 32768
    wavelet_kernel<<<blocks, 256, 0, stream>>>(x, w, out);
}

// Round 3
// 223.896 us; speedup vs baseline: 1.0001x; 1.0001x over previous
//
#include <hip/hip_runtime.h>
#include <stdint.h>

// WaveletLayer fused kernel (fp32): db2 DWT (symmetric ext) -> scale cD by
// weight[0] -> db2 IDWT -> leaky_relu(0.01).
//
// R2 structure: one 256-thread block = 2 rows of N=512; each thread owns 4
// consecutive elements (one float4). Coefficients are recomputed per-thread
// in registers (each coeff needed by 2 threads -> 2x VALU, still far under
// the memory roofline). Cross-thread halo (2 floats each side) comes from a
// TRANSPOSED LDS layout xt[4][256] (lane t holds quad t), so every LDS
// access is lane-stride-1 -> zero bank conflicts. One barrier total.
//
// Index algebra (verified, R1 passed with it):
//   cA[i] = DL3*x[2i-2] + DL2*x[2i-1] + DL1*x[2i] + DL0*x[2i+1]  (interior)
//   i=0: taps (x1,x0,x0,x1)   i=256: taps (x510,x511,x511,x510)
//   even j: z = RL2*A[i] + RL0*A[i+1] + RH2*D[i] + RH0*D[i+1],  i=j/2
//   odd  j: z = RL3*A[i] + RL1*A[i+1] + RH3*D[i] + RH1*D[i+1]
//   with D = weight[0] * cD.
// Per thread (col = 4t mod 512): needs x[col-2..col+5]; halo substitutions
// at col==0 / col==508 are the thread's own registers (reflection).

#define N   512
#define NC  257

typedef float f4v __attribute__((ext_vector_type(4)));

__global__ __launch_bounds__(256) void wavelet_kernel(
    const float* __restrict__ x,
    const float* __restrict__ w,
    float* __restrict__ out)
{
    constexpr float DL0 = -0.12940952255092145f, DL1 = 0.22414386804185735f,
                    DL2 =  0.836516303737469f,   DL3 = 0.48296291314469025f;
    constexpr float DH0 = -0.48296291314469025f, DH1 = 0.836516303737469f,
                    DH2 = -0.22414386804185735f, DH3 = -0.12940952255092145f;
    constexpr float RL0 =  0.48296291314469025f, RL1 = 0.836516303737469f,
                    RL2 =  0.22414386804185735f, RL3 = -0.12940952255092145f;
    constexpr float RH0 = -0.12940952255092145f, RH1 = -0.22414386804185735f,
                    RH2 =  0.836516303737469f,   RH3 = -0.48296291314469025f;

    __shared__ float xt[4][256];   // transposed: xt[k][t] = x[4t + k] (block-local)
    __shared__ float wf[NC];

    const int tid = threadIdx.x;
    const size_t base = (size_t)blockIdx.x * 1024;   // 2 rows * 512

    // stage weight row 0 (first NC floats of the (2,257) weight)
    wf[tid] = w[tid];
    if (tid == 0) wf[256] = w[256];

    // global -> registers -> transposed LDS (all lane-stride-1, no conflicts)
    f4v v = __builtin_nontemporal_load(((const f4v*)(x + base)) + tid);
    xt[0][tid] = v.x;
    xt[1][tid] = v.y;
    xt[2][tid] = v.z;
    xt[3][tid] = v.w;
    __syncthreads();

    const int col = (tid << 2) & (N - 1);        // 0..508, step 4
    const int lm = (tid == 0)   ? 0   : tid - 1; // clamp (value unused when clamped)
    const int lp = (tid == 255) ? 255 : tid + 1;

    float xl0 = xt[2][lm], xl1 = xt[3][lm];      // x[col-2], x[col-1]
    float xr0 = xt[0][lp], xr1 = xt[1][lp];      // x[col+4], x[col+5]

    // boundary reflections collapse to own-register substitutions
    if (col == 0)     { xl0 = v.y; xl1 = v.x; }  // i=0 taps -> (x1,x0,x0,x1)
    if (col == N - 4) { xr0 = v.w; xr1 = v.z; }  // i=256 taps -> (x510,x511,x511,x510)

    // three coefficient pairs: i0 = col/2, i0+1, i0+2
    float A0 = DL3 * xl0 + DL2 * xl1 + DL1 * v.x + DL0 * v.y;
    float D0 = DH3 * xl0 + DH2 * xl1 + DH1 * v.x + DH0 * v.y;
    float A1 = DL3 * v.x + DL2 * v.y + DL1 * v.z + DL0 * v.w;
    float D1 = DH3 * v.x + DH2 * v.y + DH1 * v.z + DH0 * v.w;
    float A2 = DL3 * v.z + DL2 * v.w + DL1 * xr0 + DL0 * xr1;
    float D2 = DH3 * v.z + DH2 * v.w + DH1 * xr0 + DH0 * xr1;

    const int i0 = col >> 1;                     // wf reads: stride-2 lanes = free 2-way
    D0 *= wf[i0];
    D1 *= wf[i0 + 1];
    D2 *= wf[i0 + 2];

    // IDWT + leaky_relu, 4 consecutive outputs
    float z0 = RL2 * A0 + RL0 * A1 + RH2 * D0 + RH0 * D1;
    float z1 = RL3 * A0 + RL1 * A1 + RH3 * D0 + RH1 * D1;
    float z2 = RL2 * A1 + RL0 * A2 + RH2 * D1 + RH0 * D2;
    float z3 = RL3 * A1 + RL1 * A2 + RH3 * D1 + RH1 * D2;

    f4v o;
    o.x = z0 >= 0.f ? z0 : 0.01f * z0;
    o.y = z1 >= 0.f ? z1 : 0.01f * z1;
    o.z = z2 >= 0.f ? z2 : 0.01f * z2;
    o.w = z3 >= 0.f ? z3 : 0.01f * z3;
    __builtin_nontemporal_store(o, ((f4v*)(out + base)) + tid);
}

extern "C" void kernel_launch(void* const* d_in, const int* in_sizes, int n_in,
                              void* d_out, int out_size, void* d_ws, size_t ws_size,
                              hipStream_t stream) {
    const float* x = (const float*)d_in[0];
    const float* w = (const float*)d_in[1];
    float* out = (float*)d_out;

    int blocks = in_sizes[0] / 1024;   // 65536 rows * 512 / (2 rows * 512) = 32768
    wavelet_kernel<<<blocks, 256, 0, stream>>>(x, w, out);
}